// Round 12
// baseline (300.960 us; speedup 1.0000x reference)
//
#include <hip/hip_runtime.h>
#include <cstdint>
#include <cstddef>

// ---- problem constants ----
#define EMB   1024
#define NH    16
#define HD    64
#define SEQ   2048
#define NB    4
#define MROWS 8192   // NB*SEQ

typedef short short8 __attribute__((ext_vector_type(8)));
typedef float floatx4 __attribute__((ext_vector_type(4)));

// round-to-nearest bf16: 1 VALU op + hi16 store
__device__ __forceinline__ unsigned short f2bf(float f) {
  return (unsigned short)((__float_as_uint(f) + 0x8000u) >> 16);
}

// async global->LDS, 16B per lane; LDS dest = wave-uniform base + lane*16
__device__ __forceinline__ void load16_lds(const unsigned short* g, unsigned short* l) {
  __builtin_amdgcn_global_load_lds((const __attribute__((address_space(1))) void*)g,
                                   (__attribute__((address_space(3))) void*)l, 16, 0, 0);
}

// ---------------- fused prelude: W-transpose x4 + x-convert + time-weights, ONE launch ----------------
// r11-verified (278.6 us total). Work mappings byte-identical to the r10 versions:
//   z in [0,4): transpose_convert4 (tx = tid&31, ty = tid>>5 reproduces dim3(32,8))
//   z in [4,12): convert_x with blk = (z-4)*1024 + by*32 + bx  (bijective over 8192)
//   block (0,0,0) additionally runs time_weights on tid<64 after its transpose work.
__global__ void prelude_kernel(const float* __restrict__ x, unsigned short* __restrict__ xout,
                               const float* __restrict__ Wq, const float* __restrict__ Wk,
                               const float* __restrict__ Wv, const float* __restrict__ Wo,
                               unsigned short* __restrict__ wqkvt, unsigned short* __restrict__ wot,
                               const float* __restrict__ te, const float* __restrict__ Wt,
                               const float* __restrict__ bt, float* __restrict__ tw) {
  const int tid = threadIdx.x;
  const int z = blockIdx.z;
  if (z >= 4) {
    // ---- x (fp32) -> bf16, 8 B out/thread ----
    const int blk = (z - 4) * 1024 + blockIdx.y * 32 + blockIdx.x;
    const int i = blk * 256 + tid;
    float4 v = ((const float4*)x)[i];
    unsigned int u0 = __float_as_uint(v.x) + 0x8000u, u1 = __float_as_uint(v.y) + 0x8000u;
    unsigned int u2 = __float_as_uint(v.z) + 0x8000u, u3 = __float_as_uint(v.w) + 0x8000u;
    uint2 p;
    p.x = (u0 >> 16) | (u1 & 0xffff0000u);
    p.y = (u2 >> 16) | (u3 & 0xffff0000u);
    *(uint2*)&xout[(size_t)i * 4] = p;
    return;
  }
  // ---- W [K][N] fp32 -> W^T [N][K] bf16 (32x32 tile via LDS) ----
  __shared__ float tile[32][33];
  const float* W = (z == 0) ? Wq : (z == 1) ? Wk : (z == 2) ? Wv : Wo;
  unsigned short* out = (z < 3) ? (wqkvt + (size_t)z * EMB * EMB) : wot;
  const int k0 = blockIdx.x * 32;
  const int n0 = blockIdx.y * 32;
  const int tx = tid & 31;   // 0..31
  const int ty = tid >> 5;   // 0..7
#pragma unroll
  for (int i = 0; i < 4; i++) {
    int k = ty + i * 8;
    tile[k][tx] = W[(size_t)(k0 + k) * EMB + n0 + tx];
  }
  __syncthreads();
#pragma unroll
  for (int i = 0; i < 4; i++) {
    int n = ty + i * 8;
    out[(size_t)(n0 + n) * EMB + k0 + tx] = f2bf(tile[tx][n]);
  }
  // ---- time weights, once (block 0,0,0; wave 0) ----
  if (z == 0 && blockIdx.x == 0 && blockIdx.y == 0 && tid < 64) {
    int b = tid >> 4, h = tid & 15;
    float acc = bt[h];
    for (int i = 0; i < 128; i++) acc += te[b * 128 + i] * Wt[i * 16 + h];
    float m = acc;
    for (int off = 1; off < 16; off <<= 1) m = fmaxf(m, __shfl_xor(m, off, 16));
    float e = __expf(acc - m);
    float s = e;
    for (int off = 1; off < 16; off <<= 1) s += __shfl_xor(s, off, 16);
    tw[tid] = (e / s) * 0.125f * 1.4426950408889634f;  // 1/sqrt(64) * log2(e)
  }
}

// ---------------- GEMM: C[M][N] = A[M][K=1024] @ Bt[N][K=1024]^T ----------------
// r12: same verified 4-phase K-loop (r3/r4/r7/r10/r11), two packing changes:
//  (a) __launch_bounds__(256,3): 3 blocks/CU (LDS 48KB x3 = 144 <= 160 KB). gemm<0>'s
//      768 blocks now fill 768 slots exactly -> 1 round (was 1.5 rounds at 2/CU = 75%
//      block-slot utilization). VGPR cap 512/3 ~= 170.
//  (b) to fit the cap, b0F's live range is cut: P3 (which had no ds_reads) RE-READS
//      b0F from LDS instead of holding it across P1/P2 (-8 live VGPR, +2 b128 reads in
//      an empty slot). WAR check: cur-buffer b0/b1 regions are overwritten only by
//      tile t+2 staging issued at t+1's P1, which is after t's closing barrier. P3 now
//      gets the same lgkmcnt(0)+sched_barrier gate before its MFMAs.
// 128 KiB dynamic-LDS variant PERMANENTLY ABANDONED (container died 2/2: r1, r9).
// No setprio (r7 A/B: -6% on lockstep structures).
template <int EPI>
__global__ __launch_bounds__(256, 3) void gemm_kernel(
    const unsigned short* __restrict__ A, const unsigned short* __restrict__ Bt,
    unsigned short* __restrict__ qo, unsigned short* __restrict__ ko, unsigned short* __restrict__ vto,
    float* __restrict__ outf, const float* __restrict__ bias, const float* __restrict__ tw) {
  __shared__ unsigned short ldsu[24576];   // 48 KiB: per buf {A 4096 | B 8192} shorts, x2

  const int tid = threadIdx.x;
  const int lane = tid & 63, wid = tid >> 6;    // wid = wn in 0..3
  const int quad = lane >> 4, l16 = lane & 15;

  // XCD-aware swizzle; bijective since nwg % 8 == 0 (768 and 256)
  const int gx = gridDim.x;
  const int nwg = gx * gridDim.y;
  const int fid = blockIdx.y * gx + blockIdx.x;
  const int swzid = (fid & 7) * (nwg >> 3) + (fid >> 3);
  const int m0 = (swzid / gx) * 128;
  const int n0 = (swzid % gx) * 256;

  // staging: thread covers row trow (0..63) of a 64-row chunk, phys granule tid&3;
  // source granule pre-swizzled = (tid&3) ^ swz(trow); chunk row-offsets are multiples
  // of 64 so swz is chunk-invariant.
  const int trow = tid >> 2;   // 0..63
  const int sw = ((tid & 3) ^ ((tid >> 2) & 3) ^ ((tid >> 4) & 3)) * 8;
  const unsigned short* gA = A + (size_t)(m0 + trow) * 1024 + sw;    // + 65536 per 64 rows
  const unsigned short* gB = Bt + (size_t)(n0 + trow) * 1024 + sw;   // + c*65536 per chunk
  unsigned short* lw = ldsu + (wid << 9);   // wave's slice base within each chunk region
  // chunk LDS regions (shorts): a0 @0, a1 @2048, b0 @4096, b1 @6144, b2 @8192, b3 @10240

  // frag reads: row R (R&15 == l16, bases %16==0), phys granule quad ^ swz(l16)
  const int swl = (l16 & 3) ^ (l16 >> 2);
  const int foff = (quad ^ swl) * 8;
  const int abase = l16 * 32 + foff;                         // + mh*2048 + mi*512
  const int bbase = 4096 + wid * 1024 + l16 * 32 + foff;     // + nh*4096 + ni*512

  floatx4 acc[8][4];   // [mh*4+mi][nh*2+ni]
#pragma unroll
  for (int mi = 0; mi < 8; mi++)
#pragma unroll
    for (int ni = 0; ni < 4; ni++)
#pragma unroll
      for (int r = 0; r < 4; r++) acc[mi][ni][r] = 0.f;

  // prologue: stage tile 0 into buf0, order b0,b1,a0,b2,b3,a1; keep newest 3 in flight
  load16_lds(gB, lw + 4096);
  load16_lds(gB + 65536, lw + 6144);
  load16_lds(gA, lw);
  load16_lds(gB + 131072, lw + 8192);
  load16_lds(gB + 196608, lw + 10240);
  load16_lds(gA + 65536, lw + 2048);
  asm volatile("s_waitcnt vmcnt(3)" ::: "memory");
  asm volatile("s_barrier" ::: "memory");

  short8 aF[4], b0F[2], b1F[2];
  for (int t = 0; t < 32; ++t) {
    const int cur = (t & 1) ? 12288 : 0;
    const int nxt = (t & 1) ? 0 : 12288;
    const int kc = ((t + 1) & 31) * 32;   // t=31 wraps: junk into dead buffer

    // ---- P0: read A-mh0 + B-nh0; issue b0,b1(t+1); vmcnt(3) drains b2,b3(t)
#pragma unroll
    for (int mi = 0; mi < 4; mi++) aF[mi] = *(const short8*)&ldsu[cur + abase + mi * 512];
#pragma unroll
    for (int ni = 0; ni < 2; ni++) b0F[ni] = *(const short8*)&ldsu[cur + bbase + ni * 512];
    load16_lds(gB + kc, lw + nxt + 4096);
    load16_lds(gB + 65536 + kc, lw + nxt + 6144);
    asm volatile("s_waitcnt vmcnt(3)" ::: "memory");
    asm volatile("s_barrier" ::: "memory");
    asm volatile("s_waitcnt lgkmcnt(0)" ::: "memory");
    __builtin_amdgcn_sched_barrier(0);
#pragma unroll
    for (int mi = 0; mi < 4; mi++)
#pragma unroll
      for (int ni = 0; ni < 2; ni++)
        acc[mi][ni] = __builtin_amdgcn_mfma_f32_16x16x32_bf16(aF[mi], b0F[ni], acc[mi][ni], 0, 0, 0);
    asm volatile("s_barrier" ::: "memory");

    // ---- P1: read B-nh1; issue a0,b2(t+1); vmcnt(4) drains a1(t)
#pragma unroll
    for (int ni = 0; ni < 2; ni++) b1F[ni] = *(const short8*)&ldsu[cur + bbase + 4096 + ni * 512];
    load16_lds(gA + kc, lw + nxt);
    load16_lds(gB + 131072 + kc, lw + nxt + 8192);
    asm volatile("s_waitcnt vmcnt(4)" ::: "memory");
    asm volatile("s_barrier" ::: "memory");
    asm volatile("s_waitcnt lgkmcnt(0)" ::: "memory");
    __builtin_amdgcn_sched_barrier(0);
#pragma unroll
    for (int mi = 0; mi < 4; mi++)
#pragma unroll
      for (int ni = 0; ni < 2; ni++)
        acc[mi][2 + ni] = __builtin_amdgcn_mfma_f32_16x16x32_bf16(aF[mi], b1F[ni], acc[mi][2 + ni], 0, 0, 0);
    asm volatile("s_barrier" ::: "memory");

    // ---- P2: read A-mh1; issue b3(t+1); no wait needed
#pragma unroll
    for (int mi = 0; mi < 4; mi++) aF[mi] = *(const short8*)&ldsu[cur + abase + 2048 + mi * 512];
    load16_lds(gB + 196608 + kc, lw + nxt + 10240);
    asm volatile("s_barrier" ::: "memory");
    asm volatile("s_waitcnt lgkmcnt(0)" ::: "memory");
    __builtin_amdgcn_sched_barrier(0);
#pragma unroll
    for (int mi = 0; mi < 4; mi++)
#pragma unroll
      for (int ni = 0; ni < 2; ni++)
        acc[4 + mi][2 + ni] = __builtin_amdgcn_mfma_f32_16x16x32_bf16(aF[mi], b1F[ni], acc[4 + mi][2 + ni], 0, 0, 0);
    asm volatile("s_barrier" ::: "memory");

    // ---- P3: RE-READ B-nh0 (live-range cut); issue a1(t+1); vmcnt(3) drains b0,b1,a0(t+1)
#pragma unroll
    for (int ni = 0; ni < 2; ni++) b0F[ni] = *(const short8*)&ldsu[cur + bbase + ni * 512];
    load16_lds(gA + 65536 + kc, lw + nxt + 2048);
    asm volatile("s_waitcnt vmcnt(3)" ::: "memory");
    asm volatile("s_barrier" ::: "memory");
    asm volatile("s_waitcnt lgkmcnt(0)" ::: "memory");
    __builtin_amdgcn_sched_barrier(0);
#pragma unroll
    for (int mi = 0; mi < 4; mi++)
#pragma unroll
      for (int ni = 0; ni < 2; ni++)
        acc[4 + mi][ni] = __builtin_amdgcn_mfma_f32_16x16x32_bf16(aF[mi], b0F[ni], acc[4 + mi][ni], 0, 0, 0);
    asm volatile("s_barrier" ::: "memory");
  }
  // never end the wave with async LDS-writes in flight
  asm volatile("s_waitcnt vmcnt(0)" ::: "memory");

  // epilogue.  C[row = quad*4+r (M), col = l16 (N)] per 16x16 tile.
  // wave's col for ni' = nh*2+nl: n = n0 + nh*128 + wid*32 + nl*16 + l16
  if (EPI == 1) {
#pragma unroll
    for (int ni = 0; ni < 4; ni++) {
      const int n = n0 + (ni >> 1) * 128 + wid * 32 + (ni & 1) * 16 + l16;
      const float bs = bias[n];
#pragma unroll
      for (int mi = 0; mi < 8; mi++) {
        const int mb = m0 + mi * 16 + quad * 4;
#pragma unroll
        for (int r = 0; r < 4; r++)
          outf[(size_t)(mb + r) * EMB + n] = acc[mi][ni][r] + bs;
      }
    }
  } else {
    const int proj = n0 >> 10;                    // block-uniform (BN=256 | 1024)
    const int b = m0 >> 11;                       // block-uniform (BM=128 | 2048)
    const int sb = (m0 & 2047) + quad * 4;
    if (proj == 0) {
#pragma unroll
      for (int ni = 0; ni < 4; ni++) {
        const int nb = n0 + (ni >> 1) * 128 + wid * 32 + (ni & 1) * 16;   // + l16
        const int hh = (nb >> 6) & 15;
        const int d = (nb & 63) + l16;
        const size_t bh = (size_t)b * NH + hh;
        const float tws = tw[bh];
#pragma unroll
        for (int mi = 0; mi < 8; mi++) {
          const int s = sb + mi * 16;
          unsigned short* qp = qo + (bh * SEQ + s) * HD + d;
#pragma unroll
          for (int r = 0; r < 4; r++) qp[(size_t)r * HD] = f2bf(acc[mi][ni][r] * tws);
        }
      }
    } else if (proj == 1) {
#pragma unroll
      for (int ni = 0; ni < 4; ni++) {
        const int nb = n0 + (ni >> 1) * 128 + wid * 32 + (ni & 1) * 16;
        const int hh = (nb >> 6) & 15;
        const int d = (nb & 63) + l16;
        const size_t bh = (size_t)b * NH + hh;
#pragma unroll
        for (int mi = 0; mi < 8; mi++) {
          const int s = sb + mi * 16;
          unsigned short* kp = ko + (bh * SEQ + s) * HD + d;
#pragma unroll
          for (int r = 0; r < 4; r++) kp[(size_t)r * HD] = f2bf(acc[mi][ni][r]);
        }
      }
    } else {
      // v: r=0..3 are s-consecutive at fixed d -> pack to one 8B store in vt[bh][d][s]
#pragma unroll
      for (int ni = 0; ni < 4; ni++) {
        const int nb = n0 + (ni >> 1) * 128 + wid * 32 + (ni & 1) * 16;
        const int hh = (nb >> 6) & 15;
        const int d = (nb & 63) + l16;
        const size_t bh = (size_t)b * NH + hh;
#pragma unroll
        for (int mi = 0; mi < 8; mi++) {
          const int s = sb + mi * 16;
          unsigned int u0 = __float_as_uint(acc[mi][ni][0]) + 0x8000u;
          unsigned int u1 = __float_as_uint(acc[mi][ni][1]) + 0x8000u;
          unsigned int u2 = __float_as_uint(acc[mi][ni][2]) + 0x8000u;
          unsigned int u3 = __float_as_uint(acc[mi][ni][3]) + 0x8000u;
          uint2 w;
          w.x = (u0 >> 16) | (u1 & 0xffff0000u);
          w.y = (u2 >> 16) | (u3 & 0xffff0000u);
          *(uint2*)&vto[(bh * HD + d) * SEQ + s] = w;
        }
      }
    }
  }
}

// ---------------- flash attention (no-max softmax; S and O both computed transposed) ----------------
// r12 == r11 attn verbatim (99.5-99.9 us; FETCH 25.9 MB): r4-exact compute + XCD-locality
// block remap. r10/r11 post-mortem: attn is serial-chain-bound (FETCH fell 5.5x, dur -1%;
// all LDS patterns verified at wave64 bank minimum, the 6.29M counter is free 2-ways).
// setprio removed (r7: -6%); cvt_pk + ones-MFMA permanently reverted (r5 absmax).
__global__ __launch_bounds__(256, 4) void attn_kernel(
    const unsigned short* __restrict__ qg, const unsigned short* __restrict__ kg,
    const unsigned short* __restrict__ vtg, unsigned short* __restrict__ aog) {
  __shared__ unsigned short Ks[64 * 64];    // 8 KB; [key][d], granule swizzle g^=(row&7)
  __shared__ unsigned short Vs[64 * 64];    // 8 KB; [d][key], granule swizzle g^=(row&7)
  __shared__ unsigned short Ps[4 * 2048];   // 16 KB; per-wave P^T 32 qrows x 64 keys,
                                            //   4-key chunk swizzle c^=(qrow&14)
  // total 32768 B -> LDS allows 5 blocks/CU; grid 1024 = 4/CU co-resident, no tail

  int tid = threadIdx.x;
  int lane = tid & 63, wid = tid >> 6;
  int quad = lane >> 4, l16 = lane & 15, l7 = lane & 7;

  // XCD-locality remap (bijective on 1024 blocks)
  int L = blockIdx.x + 16 * blockIdx.y + 256 * blockIdx.z;
  int qt = L >> 6;
  int rr = L & 63;
  int bh = (rr & 7) * 8 + (rr >> 3);
  int h = bh & 15, b = bh >> 4;

  const unsigned short* qbase = qg + (size_t)bh * SEQ * HD + (size_t)qt * 128 * HD;
  const unsigned short* kbase = kg + (size_t)bh * SEQ * HD;
  const unsigned short* vbase = vtg + (size_t)bh * HD * SEQ;

  // Q B-fragments straight from global (one-time): B[n=qrow=l16][k=d=quad*8+j]
  short8 b_q[2][2];
#pragma unroll
  for (int mi = 0; mi < 2; mi++)
#pragma unroll
    for (int kk = 0; kk < 2; kk++)
      b_q[mi][kk] = *(const short8*)&qbase[(wid * 32 + mi * 16 + l16) * 64 + kk * 32 + quad * 8];

  // staging: instr c covers rows wid*16 + c*8 + lane/8, granule lane&7 ^ row&7
  const unsigned short* gK[2];
  const unsigned short* gV[2];
  unsigned short* lK[2];
  unsigned short* lV[2];
#pragma unroll
  for (int c = 0; c < 2; c++) {
    int row = wid * 16 + c * 8 + (lane >> 3);
    int gcol = ((lane & 7) ^ (row & 7)) * 8;
    gK[c] = kbase + row * 64 + gcol;            // + kb*4096 per iter
    gV[c] = vbase + (size_t)row * SEQ + gcol;   // + kb*64  per iter
    lK[c] = &Ks[(wid * 16 + c * 8) * 64];
    lV[c] = &Vs[(wid * 16 + c * 8) * 64];
  }

  // K/V frag reads: row base l16*64, phys granule (i*4+quad)^l7
  int pg[2];
#pragma unroll
  for (int i = 0; i < 2; i++) pg[i] = l16 * 64 + (((i * 4 + quad) ^ l7) * 8);

  // P^T addressing (shorts). wave base + row l16 (+ mi*16 rows = mi*1024 shorts)
  int wbase = wid * 2048;
  int chunkx = l16 & 14;
  int pwa[4];   // write: chunk (ni*4+quad) ^ chunkx
#pragma unroll
  for (int ni = 0; ni < 4; ni++)
    pwa[ni] = wbase + l16 * 64 + (((ni * 4 + quad) ^ chunkx) * 4);
  int pra[2];   // read: chunk pair (kk2*8+quad*2) ^ chunkx
#pragma unroll
  for (int kk2 = 0; kk2 < 2; kk2++)
    pra[kk2] = wbase + l16 * 64 + (((kk2 * 8 + quad * 2) ^ chunkx) * 4);

  floatx4 O[4][2];   // [di][mi]  (O^T: row=d, col=qrow)
  float lsum[2] = {0.f, 0.f};
#pragma unroll
  for (int di = 0; di < 4; di++)
#pragma unroll
    for (int mi = 0; mi < 2; mi++)
#pragma unroll
      for (int r = 0; r < 4; r++) O[di][mi][r] = 0.f;

  // prologue: stage tile 0 via global_load_lds (one-time exposed latency)
  load16_lds(gK[0], lK[0]);
  load16_lds(gK[1], lK[1]);
  load16_lds(gV[0], lV[0]);
  load16_lds(gV[1], lV[1]);
  asm volatile("s_waitcnt vmcnt(0)" ::: "memory");
  __syncthreads();

  for (int kb = 0; kb < 32; kb++) {
    // issue next-tile loads to REGS now; they land during the compute below
    const int kn = (kb + 1) & 31;
    short8 kreg0 = *(const short8*)(gK[0] + kn * 4096);
    short8 kreg1 = *(const short8*)(gK[1] + kn * 4096);
    short8 vreg0 = *(const short8*)(gV[0] + kn * 64);
    short8 vreg1 = *(const short8*)(gV[1] + kn * 64);

    // S^T = K @ Q^T : 64 keys (4 m-tiles) x 32 qrows (2 n-tiles)
    floatx4 st[4][2];
#pragma unroll
    for (int ni = 0; ni < 4; ni++)
#pragma unroll
      for (int mi = 0; mi < 2; mi++)
#pragma unroll
        for (int r = 0; r < 4; r++) st[ni][mi][r] = 0.f;
#pragma unroll
    for (int kk = 0; kk < 2; kk++)
#pragma unroll
      for (int ni = 0; ni < 4; ni++) {
        short8 a_k = *(const short8*)&Ks[ni * 1024 + pg[kk]];
#pragma unroll
        for (int mi = 0; mi < 2; mi++)
          st[ni][mi] = __builtin_amdgcn_mfma_f32_16x16x32_bf16(a_k, b_q[mi][kk], st[ni][mi], 0, 0, 0);
      }

    // P = exp2(S) (|S| <~ 10, no max needed); pack 4 keys -> one b64 write to P^T
#pragma unroll
    for (int mi = 0; mi < 2; mi++)
#pragma unroll
      for (int ni = 0; ni < 4; ni++) {
        float p0 = __builtin_amdgcn_exp2f(st[ni][mi][0]);
        float p1 = __builtin_amdgcn_exp2f(st[ni][mi][1]);
        float p2 = __builtin_amdgcn_exp2f(st[ni][mi][2]);
        float p3 = __builtin_amdgcn_exp2f(st[ni][mi][3]);
        lsum[mi] += (p0 + p1) + (p2 + p3);
        unsigned int u0 = __float_as_uint(p0) + 0x8000u, u1 = __float_as_uint(p1) + 0x8000u;
        unsigned int u2 = __float_as_uint(p2) + 0x8000u, u3 = __float_as_uint(p3) + 0x8000u;
        uint2 w;
        w.x = (u0 >> 16) | (u1 & 0xffff0000u);
        w.y = (u2 >> 16) | (u3 & 0xffff0000u);
        *(uint2*)&Ps[pwa[ni] + mi * 1024] = w;
      }
    asm volatile("s_waitcnt lgkmcnt(0)" ::: "memory");  // P writes land before reads (per-wave region)

    // O^T += (V^T)(P^T):  A = V^T frag (m=d, k=key), B = P^T frag (n=qrow, k=key)
#pragma unroll
    for (int kk2 = 0; kk2 < 2; kk2++) {
      short8 av[4], bp[2];
#pragma unroll
      for (int di = 0; di < 4; di++)
        av[di] = *(const short8*)&Vs[di * 1024 + pg[kk2]];
#pragma unroll
      for (int mi = 0; mi < 2; mi++)
        bp[mi] = *(const short8*)&Ps[pra[kk2] + mi * 1024];
#pragma unroll
      for (int di = 0; di < 4; di++)
#pragma unroll
        for (int mi = 0; mi < 2; mi++)
          O[di][mi] = __builtin_amdgcn_mfma_f32_16x16x32_bf16(av[di], bp[mi], O[di][mi], 0, 0, 0);
    }

    __syncthreads();   // all waves' Ks/Vs reads done (also drains vmcnt: kregs/vregs ready)
    *(short8*)&lK[0][lane * 8] = kreg0;
    *(short8*)&lK[1][lane * 8] = kreg1;
    *(short8*)&lV[0][lane * 8] = vreg0;
    *(short8*)&lV[1][lane * 8] = vreg1;
    __syncthreads();   // staged tiles visible
  }

  // lsum: lanes sharing qrow are {l16, l16+16, l16+32, l16+48} -> 2 shuffles
  float inv[2];
#pragma unroll
  for (int mi = 0; mi < 2; mi++) {
    lsum[mi] += __shfl_xor(lsum[mi], 16);
    lsum[mi] += __shfl_xor(lsum[mi], 32);
    inv[mi] = 1.0f / lsum[mi];
  }

  // epilogue: lane holds qrow = mi*16+l16, d = di*16+quad*4+r -> 4 packed bf16 per store
#pragma unroll
  for (int mi = 0; mi < 2; mi++) {
    int s = qt * 128 + wid * 32 + mi * 16 + l16;
    size_t rowbase = ((size_t)(b * SEQ + s) * NH + h) * HD;
#pragma unroll
    for (int di = 0; di < 4; di++) {
      unsigned int u0 = __float_as_uint(O[di][mi][0] * inv[mi]) + 0x8000u;
      unsigned int u1 = __float_as_uint(O[di][mi][1] * inv[mi]) + 0x8000u;
      unsigned int u2 = __float_as_uint(O[di][mi][2] * inv[mi]) + 0x8000u;
      unsigned int u3 = __float_as_uint(O[di][mi][3] * inv[mi]) + 0x8000u;
      uint2 w;
      w.x = (u0 >> 16) | (u1 & 0xffff0000u);
      w.y = (u2 >> 16) | (u3 & 0xffff0000u);
      *(uint2*)&aog[rowbase + di * 16 + quad * 4] = w;
    }
  }
}

// ---------------- launch ----------------
extern "C" void kernel_launch(void* const* d_in, const int* in_sizes, int n_in,
                              void* d_out, int out_size, void* d_ws, size_t ws_size,
                              hipStream_t stream) {
  (void)in_sizes; (void)n_in; (void)out_size; (void)ws_size;
  const float* x  = (const float*)d_in[0];
  const float* te = (const float*)d_in[1];
  const float* Wq = (const float*)d_in[2];
  const float* Wk = (const float*)d_in[3];
  const float* Wv = (const float*)d_in[4];
  const float* Wo = (const float*)d_in[5];
  const float* bo = (const float*)d_in[6];
  const float* Wt = (const float*)d_in[7];
  const float* bt = (const float*)d_in[8];
  float* out = (float*)d_out;

  char* ws = (char*)d_ws;
  size_t off = 0;
  auto carve = [&](size_t bytes) -> void* {
    void* p = ws + off;
    off += (bytes + 255) & ~(size_t)255;
    return p;
  };
  float* twb            = (float*)carve(64 * sizeof(float));
  unsigned short* xb    = (unsigned short*)carve((size_t)MROWS * EMB * 2);   // 16 MB
  unsigned short* wqkvt = (unsigned short*)carve((size_t)3 * EMB * EMB * 2); //  6 MB
  unsigned short* wot   = (unsigned short*)carve((size_t)EMB * EMB * 2);     //  2 MB
  unsigned short* vtb   = (unsigned short*)carve((size_t)MROWS * EMB * 2);   // 16 MB
  // q/k live in d_out (8192*1024 fp32 = 32 MB = 2 * 16 MB bf16); both are dead before
  // gemm<1> overwrites d_out with the final result.
  unsigned short* qb    = (unsigned short*)d_out;
  unsigned short* kb    = (unsigned short*)d_out + (size_t)MROWS * EMB;
  unsigned short* ao    = xb;  // alias: xb is dead after GEMM0

  prelude_kernel<<<dim3(32, 32, 12), dim3(256), 0, stream>>>(
      x, xb, Wq, Wk, Wv, Wo, wqkvt, wot, te, Wt, bt, twb);
  gemm_kernel<0><<<dim3(12, 64), dim3(256), 0, stream>>>(xb, wqkvt, qb, kb, vtb, nullptr, nullptr, twb);
  attn_kernel<<<dim3(16, NH, NB), dim3(256), 0, stream>>>(qb, kb, vtb, ao);
  gemm_kernel<1><<<dim3(4, 64), dim3(256), 0, stream>>>(ao, wot, nullptr, nullptr, nullptr, out, bo, nullptr);
}

// Round 13
// 276.695 us; speedup vs baseline: 1.0877x; 1.0877x over previous
//
#include <hip/hip_runtime.h>
#include <cstdint>
#include <cstddef>

// ---- problem constants ----
#define EMB   1024
#define NH    16
#define HD    64
#define SEQ   2048
#define NB    4
#define MROWS 8192   // NB*SEQ

typedef short short8 __attribute__((ext_vector_type(8)));
typedef float floatx4 __attribute__((ext_vector_type(4)));

// round-to-nearest bf16: 1 VALU op + hi16 store
__device__ __forceinline__ unsigned short f2bf(float f) {
  return (unsigned short)((__float_as_uint(f) + 0x8000u) >> 16);
}

// async global->LDS, 16B per lane; LDS dest = wave-uniform base + lane*16
__device__ __forceinline__ void load16_lds(const unsigned short* g, unsigned short* l) {
  __builtin_amdgcn_global_load_lds((const __attribute__((address_space(1))) void*)g,
                                   (__attribute__((address_space(3))) void*)l, 16, 0, 0);
}

// ---------------- fused prelude: W-transpose x4 + x-convert + time-weights, ONE launch ----------------
// r11-verified (278.6 us total). Work mappings byte-identical to the r10 versions:
//   z in [0,4): transpose_convert4 (tx = tid&31, ty = tid>>5 reproduces dim3(32,8))
//   z in [4,12): convert_x with blk = (z-4)*1024 + by*32 + bx  (bijective over 8192)
//   block (0,0,0) additionally runs time_weights on tid<64 after its transpose work.
__global__ void prelude_kernel(const float* __restrict__ x, unsigned short* __restrict__ xout,
                               const float* __restrict__ Wq, const float* __restrict__ Wk,
                               const float* __restrict__ Wv, const float* __restrict__ Wo,
                               unsigned short* __restrict__ wqkvt, unsigned short* __restrict__ wot,
                               const float* __restrict__ te, const float* __restrict__ Wt,
                               const float* __restrict__ bt, float* __restrict__ tw) {
  const int tid = threadIdx.x;
  const int z = blockIdx.z;
  if (z >= 4) {
    // ---- x (fp32) -> bf16, 8 B out/thread ----
    const int blk = (z - 4) * 1024 + blockIdx.y * 32 + blockIdx.x;
    const int i = blk * 256 + tid;
    float4 v = ((const float4*)x)[i];
    unsigned int u0 = __float_as_uint(v.x) + 0x8000u, u1 = __float_as_uint(v.y) + 0x8000u;
    unsigned int u2 = __float_as_uint(v.z) + 0x8000u, u3 = __float_as_uint(v.w) + 0x8000u;
    uint2 p;
    p.x = (u0 >> 16) | (u1 & 0xffff0000u);
    p.y = (u2 >> 16) | (u3 & 0xffff0000u);
    *(uint2*)&xout[(size_t)i * 4] = p;
    return;
  }
  // ---- W [K][N] fp32 -> W^T [N][K] bf16 (32x32 tile via LDS) ----
  __shared__ float tile[32][33];
  const float* W = (z == 0) ? Wq : (z == 1) ? Wk : (z == 2) ? Wv : Wo;
  unsigned short* out = (z < 3) ? (wqkvt + (size_t)z * EMB * EMB) : wot;
  const int k0 = blockIdx.x * 32;
  const int n0 = blockIdx.y * 32;
  const int tx = tid & 31;   // 0..31
  const int ty = tid >> 5;   // 0..7
#pragma unroll
  for (int i = 0; i < 4; i++) {
    int k = ty + i * 8;
    tile[k][tx] = W[(size_t)(k0 + k) * EMB + n0 + tx];
  }
  __syncthreads();
#pragma unroll
  for (int i = 0; i < 4; i++) {
    int n = ty + i * 8;
    out[(size_t)(n0 + n) * EMB + k0 + tx] = f2bf(tile[tx][n]);
  }
  // ---- time weights, once (block 0,0,0; wave 0) ----
  if (z == 0 && blockIdx.x == 0 && blockIdx.y == 0 && tid < 64) {
    int b = tid >> 4, h = tid & 15;
    float acc = bt[h];
    for (int i = 0; i < 128; i++) acc += te[b * 128 + i] * Wt[i * 16 + h];
    float m = acc;
    for (int off = 1; off < 16; off <<= 1) m = fmaxf(m, __shfl_xor(m, off, 16));
    float e = __expf(acc - m);
    float s = e;
    for (int off = 1; off < 16; off <<= 1) s += __shfl_xor(s, off, 16);
    tw[tid] = (e / s) * 0.125f * 1.4426950408889634f;  // 1/sqrt(64) * log2(e)
  }
}

// ---------------- GEMM: C[M][N] = A[M][K=1024] @ Bt[N][K=1024]^T ----------------
// r13 == r11's verified 4-phase kernel EXACTLY (passed r3/r4/r7/r10/r11 at ~95 us for
// gemm<0>). r12's packing experiment (launch_bounds(256,3) + P3 b0F re-read) REGRESSED
// -22 us total: the ~170-VGPR cap spilled inside the K-loop and the extra lgkm gate
// cost more than the 25% block-slot-utilization gain -> reverted per pre-commitment.
// 128 KiB dynamic-LDS variant PERMANENTLY ABANDONED (container died 2/2: r1, r9).
// No setprio (r7 A/B: -6% on lockstep structures).
//
// Per K-tile: P0 reads A-mh0(4)+B-nh0(2), P1 reads B-nh1(2), P2 reads A-mh1(4), P3 none.
// Staging: 6 chunks/tile; issue slots {P0: b0,b1 | P1: a0,b2 | P2: b3 | P3: a1};
// queue-simulated waits {P0: vmcnt(3), P1: vmcnt(4), P3: vmcnt(3)} -- never 0 in-loop.
// Tail t=31 wraps kc (junk into dead buffer); vmcnt(0) after the loop.
// LDS granule swizzle: P = G ^ swz(R), swz(R)=(R&3)^((R>>2)&3), via pre-swizzled source.
template <int EPI>
__global__ __launch_bounds__(256, 2) void gemm_kernel(
    const unsigned short* __restrict__ A, const unsigned short* __restrict__ Bt,
    unsigned short* __restrict__ qo, unsigned short* __restrict__ ko, unsigned short* __restrict__ vto,
    float* __restrict__ outf, const float* __restrict__ bias, const float* __restrict__ tw) {
  __shared__ unsigned short ldsu[24576];   // 48 KiB: per buf {A 4096 | B 8192} shorts, x2

  const int tid = threadIdx.x;
  const int lane = tid & 63, wid = tid >> 6;    // wid = wn in 0..3
  const int quad = lane >> 4, l16 = lane & 15;

  // XCD-aware swizzle; bijective since nwg % 8 == 0 (768 and 256)
  const int gx = gridDim.x;
  const int nwg = gx * gridDim.y;
  const int fid = blockIdx.y * gx + blockIdx.x;
  const int swzid = (fid & 7) * (nwg >> 3) + (fid >> 3);
  const int m0 = (swzid / gx) * 128;
  const int n0 = (swzid % gx) * 256;

  // staging: thread covers row trow (0..63) of a 64-row chunk, phys granule tid&3;
  // source granule pre-swizzled = (tid&3) ^ swz(trow); chunk row-offsets are multiples
  // of 64 so swz is chunk-invariant.
  const int trow = tid >> 2;   // 0..63
  const int sw = ((tid & 3) ^ ((tid >> 2) & 3) ^ ((tid >> 4) & 3)) * 8;
  const unsigned short* gA = A + (size_t)(m0 + trow) * 1024 + sw;    // + 65536 per 64 rows
  const unsigned short* gB = Bt + (size_t)(n0 + trow) * 1024 + sw;   // + c*65536 per chunk
  unsigned short* lw = ldsu + (wid << 9);   // wave's slice base within each chunk region
  // chunk LDS regions (shorts): a0 @0, a1 @2048, b0 @4096, b1 @6144, b2 @8192, b3 @10240

  // frag reads: row R (R&15 == l16, bases %16==0), phys granule quad ^ swz(l16)
  const int swl = (l16 & 3) ^ (l16 >> 2);
  const int foff = (quad ^ swl) * 8;
  const int abase = l16 * 32 + foff;                         // + mh*2048 + mi*512
  const int bbase = 4096 + wid * 1024 + l16 * 32 + foff;     // + nh*4096 + ni*512

  floatx4 acc[8][4];   // [mh*4+mi][nh*2+ni]
#pragma unroll
  for (int mi = 0; mi < 8; mi++)
#pragma unroll
    for (int ni = 0; ni < 4; ni++)
#pragma unroll
      for (int r = 0; r < 4; r++) acc[mi][ni][r] = 0.f;

  // prologue: stage tile 0 into buf0, order b0,b1,a0,b2,b3,a1; keep newest 3 in flight
  load16_lds(gB, lw + 4096);
  load16_lds(gB + 65536, lw + 6144);
  load16_lds(gA, lw);
  load16_lds(gB + 131072, lw + 8192);
  load16_lds(gB + 196608, lw + 10240);
  load16_lds(gA + 65536, lw + 2048);
  asm volatile("s_waitcnt vmcnt(3)" ::: "memory");
  asm volatile("s_barrier" ::: "memory");

  short8 aF[4], b0F[2], b1F[2];
  for (int t = 0; t < 32; ++t) {
    const int cur = (t & 1) ? 12288 : 0;
    const int nxt = (t & 1) ? 0 : 12288;
    const int kc = ((t + 1) & 31) * 32;   // t=31 wraps: junk into dead buffer

    // ---- P0: read A-mh0 + B-nh0; issue b0,b1(t+1); vmcnt(3) drains b2,b3(t)
#pragma unroll
    for (int mi = 0; mi < 4; mi++) aF[mi] = *(const short8*)&ldsu[cur + abase + mi * 512];
#pragma unroll
    for (int ni = 0; ni < 2; ni++) b0F[ni] = *(const short8*)&ldsu[cur + bbase + ni * 512];
    load16_lds(gB + kc, lw + nxt + 4096);
    load16_lds(gB + 65536 + kc, lw + nxt + 6144);
    asm volatile("s_waitcnt vmcnt(3)" ::: "memory");
    asm volatile("s_barrier" ::: "memory");
    asm volatile("s_waitcnt lgkmcnt(0)" ::: "memory");
    __builtin_amdgcn_sched_barrier(0);
#pragma unroll
    for (int mi = 0; mi < 4; mi++)
#pragma unroll
      for (int ni = 0; ni < 2; ni++)
        acc[mi][ni] = __builtin_amdgcn_mfma_f32_16x16x32_bf16(aF[mi], b0F[ni], acc[mi][ni], 0, 0, 0);
    asm volatile("s_barrier" ::: "memory");

    // ---- P1: read B-nh1; issue a0,b2(t+1); vmcnt(4) drains a1(t)
#pragma unroll
    for (int ni = 0; ni < 2; ni++) b1F[ni] = *(const short8*)&ldsu[cur + bbase + 4096 + ni * 512];
    load16_lds(gA + kc, lw + nxt);
    load16_lds(gB + 131072 + kc, lw + nxt + 8192);
    asm volatile("s_waitcnt vmcnt(4)" ::: "memory");
    asm volatile("s_barrier" ::: "memory");
    asm volatile("s_waitcnt lgkmcnt(0)" ::: "memory");
    __builtin_amdgcn_sched_barrier(0);
#pragma unroll
    for (int mi = 0; mi < 4; mi++)
#pragma unroll
      for (int ni = 0; ni < 2; ni++)
        acc[mi][2 + ni] = __builtin_amdgcn_mfma_f32_16x16x32_bf16(aF[mi], b1F[ni], acc[mi][2 + ni], 0, 0, 0);
    asm volatile("s_barrier" ::: "memory");

    // ---- P2: read A-mh1; issue b3(t+1); no wait needed
#pragma unroll
    for (int mi = 0; mi < 4; mi++) aF[mi] = *(const short8*)&ldsu[cur + abase + 2048 + mi * 512];
    load16_lds(gB + 196608 + kc, lw + nxt + 10240);
    asm volatile("s_barrier" ::: "memory");
    asm volatile("s_waitcnt lgkmcnt(0)" ::: "memory");
    __builtin_amdgcn_sched_barrier(0);
#pragma unroll
    for (int mi = 0; mi < 4; mi++)
#pragma unroll
      for (int ni = 0; ni < 2; ni++)
        acc[4 + mi][2 + ni] = __builtin_amdgcn_mfma_f32_16x16x32_bf16(aF[mi], b1F[ni], acc[4 + mi][2 + ni], 0, 0, 0);
    asm volatile("s_barrier" ::: "memory");

    // ---- P3: no reads; issue a1(t+1); vmcnt(3) drains b0,b1,a0(t+1)
    load16_lds(gA + 65536 + kc, lw + nxt + 2048);
    asm volatile("s_waitcnt vmcnt(3)" ::: "memory");
    asm volatile("s_barrier" ::: "memory");
#pragma unroll
    for (int mi = 0; mi < 4; mi++)
#pragma unroll
      for (int ni = 0; ni < 2; ni++)
        acc[4 + mi][ni] = __builtin_amdgcn_mfma_f32_16x16x32_bf16(aF[mi], b0F[ni], acc[4 + mi][ni], 0, 0, 0);
    asm volatile("s_barrier" ::: "memory");
  }
  // never end the wave with async LDS-writes in flight
  asm volatile("s_waitcnt vmcnt(0)" ::: "memory");

  // epilogue.  C[row = quad*4+r (M), col = l16 (N)] per 16x16 tile.
  // wave's col for ni' = nh*2+nl: n = n0 + nh*128 + wid*32 + nl*16 + l16
  if (EPI == 1) {
#pragma unroll
    for (int ni = 0; ni < 4; ni++) {
      const int n = n0 + (ni >> 1) * 128 + wid * 32 + (ni & 1) * 16 + l16;
      const float bs = bias[n];
#pragma unroll
      for (int mi = 0; mi < 8; mi++) {
        const int mb = m0 + mi * 16 + quad * 4;
#pragma unroll
        for (int r = 0; r < 4; r++)
          outf[(size_t)(mb + r) * EMB + n] = acc[mi][ni][r] + bs;
      }
    }
  } else {
    const int proj = n0 >> 10;                    // block-uniform (BN=256 | 1024)
    const int b = m0 >> 11;                       // block-uniform (BM=128 | 2048)
    const int sb = (m0 & 2047) + quad * 4;
    if (proj == 0) {
#pragma unroll
      for (int ni = 0; ni < 4; ni++) {
        const int nb = n0 + (ni >> 1) * 128 + wid * 32 + (ni & 1) * 16;   // + l16
        const int hh = (nb >> 6) & 15;
        const int d = (nb & 63) + l16;
        const size_t bh = (size_t)b * NH + hh;
        const float tws = tw[bh];
#pragma unroll
        for (int mi = 0; mi < 8; mi++) {
          const int s = sb + mi * 16;
          unsigned short* qp = qo + (bh * SEQ + s) * HD + d;
#pragma unroll
          for (int r = 0; r < 4; r++) qp[(size_t)r * HD] = f2bf(acc[mi][ni][r] * tws);
        }
      }
    } else if (proj == 1) {
#pragma unroll
      for (int ni = 0; ni < 4; ni++) {
        const int nb = n0 + (ni >> 1) * 128 + wid * 32 + (ni & 1) * 16;
        const int hh = (nb >> 6) & 15;
        const int d = (nb & 63) + l16;
        const size_t bh = (size_t)b * NH + hh;
#pragma unroll
        for (int mi = 0; mi < 8; mi++) {
          const int s = sb + mi * 16;
          unsigned short* kp = ko + (bh * SEQ + s) * HD + d;
#pragma unroll
          for (int r = 0; r < 4; r++) kp[(size_t)r * HD] = f2bf(acc[mi][ni][r]);
        }
      }
    } else {
      // v: r=0..3 are s-consecutive at fixed d -> pack to one 8B store in vt[bh][d][s]
#pragma unroll
      for (int ni = 0; ni < 4; ni++) {
        const int nb = n0 + (ni >> 1) * 128 + wid * 32 + (ni & 1) * 16;
        const int hh = (nb >> 6) & 15;
        const int d = (nb & 63) + l16;
        const size_t bh = (size_t)b * NH + hh;
#pragma unroll
        for (int mi = 0; mi < 8; mi++) {
          const int s = sb + mi * 16;
          unsigned int u0 = __float_as_uint(acc[mi][ni][0]) + 0x8000u;
          unsigned int u1 = __float_as_uint(acc[mi][ni][1]) + 0x8000u;
          unsigned int u2 = __float_as_uint(acc[mi][ni][2]) + 0x8000u;
          unsigned int u3 = __float_as_uint(acc[mi][ni][3]) + 0x8000u;
          uint2 w;
          w.x = (u0 >> 16) | (u1 & 0xffff0000u);
          w.y = (u2 >> 16) | (u3 & 0xffff0000u);
          *(uint2*)&vto[(bh * HD + d) * SEQ + s] = w;
        }
      }
    }
  }
}

// ---------------- flash attention (no-max softmax; S and O both computed transposed) ----------------
// r13 == r11 attn verbatim (99.5-99.9 us; FETCH 25.7 MB): r4-exact compute + XCD-locality
// block remap (all 16 q-tiles of a bh on one XCD; 8 bh x 512 KB = one XCD's 4 MB L2).
// Closed as serial-chain-bound: FETCH fell 5.5x with dur -1% (r10); both pipes <50%;
// all LDS patterns at wave64 bank minimum. setprio removed (r7: -6%); cvt_pk + ones-MFMA
// permanently reverted (r5 absmax fail).
__global__ __launch_bounds__(256, 4) void attn_kernel(
    const unsigned short* __restrict__ qg, const unsigned short* __restrict__ kg,
    const unsigned short* __restrict__ vtg, unsigned short* __restrict__ aog) {
  __shared__ unsigned short Ks[64 * 64];    // 8 KB; [key][d], granule swizzle g^=(row&7)
  __shared__ unsigned short Vs[64 * 64];    // 8 KB; [d][key], granule swizzle g^=(row&7)
  __shared__ unsigned short Ps[4 * 2048];   // 16 KB; per-wave P^T 32 qrows x 64 keys,
                                            //   4-key chunk swizzle c^=(qrow&14)
  // total 32768 B -> LDS allows 5 blocks/CU; grid 1024 = 4/CU co-resident, no tail

  int tid = threadIdx.x;
  int lane = tid & 63, wid = tid >> 6;
  int quad = lane >> 4, l16 = lane & 15, l7 = lane & 7;

  // XCD-locality remap (bijective on 1024 blocks)
  int L = blockIdx.x + 16 * blockIdx.y + 256 * blockIdx.z;
  int qt = L >> 6;
  int rr = L & 63;
  int bh = (rr & 7) * 8 + (rr >> 3);
  int h = bh & 15, b = bh >> 4;

  const unsigned short* qbase = qg + (size_t)bh * SEQ * HD + (size_t)qt * 128 * HD;
  const unsigned short* kbase = kg + (size_t)bh * SEQ * HD;
  const unsigned short* vbase = vtg + (size_t)bh * HD * SEQ;

  // Q B-fragments straight from global (one-time): B[n=qrow=l16][k=d=quad*8+j]
  short8 b_q[2][2];
#pragma unroll
  for (int mi = 0; mi < 2; mi++)
#pragma unroll
    for (int kk = 0; kk < 2; kk++)
      b_q[mi][kk] = *(const short8*)&qbase[(wid * 32 + mi * 16 + l16) * 64 + kk * 32 + quad * 8];

  // staging: instr c covers rows wid*16 + c*8 + lane/8, granule lane&7 ^ row&7
  const unsigned short* gK[2];
  const unsigned short* gV[2];
  unsigned short* lK[2];
  unsigned short* lV[2];
#pragma unroll
  for (int c = 0; c < 2; c++) {
    int row = wid * 16 + c * 8 + (lane >> 3);
    int gcol = ((lane & 7) ^ (row & 7)) * 8;
    gK[c] = kbase + row * 64 + gcol;            // + kb*4096 per iter
    gV[c] = vbase + (size_t)row * SEQ + gcol;   // + kb*64  per iter
    lK[c] = &Ks[(wid * 16 + c * 8) * 64];
    lV[c] = &Vs[(wid * 16 + c * 8) * 64];
  }

  // K/V frag reads: row base l16*64, phys granule (i*4+quad)^l7
  int pg[2];
#pragma unroll
  for (int i = 0; i < 2; i++) pg[i] = l16 * 64 + (((i * 4 + quad) ^ l7) * 8);

  // P^T addressing (shorts). wave base + row l16 (+ mi*16 rows = mi*1024 shorts)
  int wbase = wid * 2048;
  int chunkx = l16 & 14;
  int pwa[4];   // write: chunk (ni*4+quad) ^ chunkx
#pragma unroll
  for (int ni = 0; ni < 4; ni++)
    pwa[ni] = wbase + l16 * 64 + (((ni * 4 + quad) ^ chunkx) * 4);
  int pra[2];   // read: chunk pair (kk2*8+quad*2) ^ chunkx
#pragma unroll
  for (int kk2 = 0; kk2 < 2; kk2++)
    pra[kk2] = wbase + l16 * 64 + (((kk2 * 8 + quad * 2) ^ chunkx) * 4);

  floatx4 O[4][2];   // [di][mi]  (O^T: row=d, col=qrow)
  float lsum[2] = {0.f, 0.f};
#pragma unroll
  for (int di = 0; di < 4; di++)
#pragma unroll
    for (int mi = 0; mi < 2; mi++)
#pragma unroll
      for (int r = 0; r < 4; r++) O[di][mi][r] = 0.f;

  // prologue: stage tile 0 via global_load_lds (one-time exposed latency)
  load16_lds(gK[0], lK[0]);
  load16_lds(gK[1], lK[1]);
  load16_lds(gV[0], lV[0]);
  load16_lds(gV[1], lV[1]);
  asm volatile("s_waitcnt vmcnt(0)" ::: "memory");
  __syncthreads();

  for (int kb = 0; kb < 32; kb++) {
    // issue next-tile loads to REGS now; they land during the compute below
    const int kn = (kb + 1) & 31;
    short8 kreg0 = *(const short8*)(gK[0] + kn * 4096);
    short8 kreg1 = *(const short8*)(gK[1] + kn * 4096);
    short8 vreg0 = *(const short8*)(gV[0] + kn * 64);
    short8 vreg1 = *(const short8*)(gV[1] + kn * 64);

    // S^T = K @ Q^T : 64 keys (4 m-tiles) x 32 qrows (2 n-tiles)
    floatx4 st[4][2];
#pragma unroll
    for (int ni = 0; ni < 4; ni++)
#pragma unroll
      for (int mi = 0; mi < 2; mi++)
#pragma unroll
        for (int r = 0; r < 4; r++) st[ni][mi][r] = 0.f;
#pragma unroll
    for (int kk = 0; kk < 2; kk++)
#pragma unroll
      for (int ni = 0; ni < 4; ni++) {
        short8 a_k = *(const short8*)&Ks[ni * 1024 + pg[kk]];
#pragma unroll
        for (int mi = 0; mi < 2; mi++)
          st[ni][mi] = __builtin_amdgcn_mfma_f32_16x16x32_bf16(a_k, b_q[mi][kk], st[ni][mi], 0, 0, 0);
      }

    // P = exp2(S) (|S| <~ 10, no max needed); pack 4 keys -> one b64 write to P^T
#pragma unroll
    for (int mi = 0; mi < 2; mi++)
#pragma unroll
      for (int ni = 0; ni < 4; ni++) {
        float p0 = __builtin_amdgcn_exp2f(st[ni][mi][0]);
        float p1 = __builtin_amdgcn_exp2f(st[ni][mi][1]);
        float p2 = __builtin_amdgcn_exp2f(st[ni][mi][2]);
        float p3 = __builtin_amdgcn_exp2f(st[ni][mi][3]);
        lsum[mi] += (p0 + p1) + (p2 + p3);
        unsigned int u0 = __float_as_uint(p0) + 0x8000u, u1 = __float_as_uint(p1) + 0x8000u;
        unsigned int u2 = __float_as_uint(p2) + 0x8000u, u3 = __float_as_uint(p3) + 0x8000u;
        uint2 w;
        w.x = (u0 >> 16) | (u1 & 0xffff0000u);
        w.y = (u2 >> 16) | (u3 & 0xffff0000u);
        *(uint2*)&Ps[pwa[ni] + mi * 1024] = w;
      }
    asm volatile("s_waitcnt lgkmcnt(0)" ::: "memory");  // P writes land before reads (per-wave region)

    // O^T += (V^T)(P^T):  A = V^T frag (m=d, k=key), B = P^T frag (n=qrow, k=key)
#pragma unroll
    for (int kk2 = 0; kk2 < 2; kk2++) {
      short8 av[4], bp[2];
#pragma unroll
      for (int di = 0; di < 4; di++)
        av[di] = *(const short8*)&Vs[di * 1024 + pg[kk2]];
#pragma unroll
      for (int mi = 0; mi < 2; mi++)
        bp[mi] = *(const short8*)&Ps[pra[kk2] + mi * 1024];
#pragma unroll
      for (int di = 0; di < 4; di++)
#pragma unroll
        for (int mi = 0; mi < 2; mi++)
          O[di][mi] = __builtin_amdgcn_mfma_f32_16x16x32_bf16(av[di], bp[mi], O[di][mi], 0, 0, 0);
    }

    __syncthreads();   // all waves' Ks/Vs reads done (also drains vmcnt: kregs/vregs ready)
    *(short8*)&lK[0][lane * 8] = kreg0;
    *(short8*)&lK[1][lane * 8] = kreg1;
    *(short8*)&lV[0][lane * 8] = vreg0;
    *(short8*)&lV[1][lane * 8] = vreg1;
    __syncthreads();   // staged tiles visible
  }

  // lsum: lanes sharing qrow are {l16, l16+16, l16+32, l16+48} -> 2 shuffles
  float inv[2];
#pragma unroll
  for (int mi = 0; mi < 2; mi++) {
    lsum[mi] += __shfl_xor(lsum[mi], 16);
    lsum[mi] += __shfl_xor(lsum[mi], 32);
    inv[mi] = 1.0f / lsum[mi];
  }

  // epilogue: lane holds qrow = mi*16+l16, d = di*16+quad*4+r -> 4 packed bf16 per store
#pragma unroll
  for (int mi = 0; mi < 2; mi++) {
    int s = qt * 128 + wid * 32 + mi * 16 + l16;
    size_t rowbase = ((size_t)(b * SEQ + s) * NH + h) * HD;
#pragma unroll
    for (int di = 0; di < 4; di++) {
      unsigned int u0 = __float_as_uint(O[di][mi][0] * inv[mi]) + 0x8000u;
      unsigned int u1 = __float_as_uint(O[di][mi][1] * inv[mi]) + 0x8000u;
      unsigned int u2 = __float_as_uint(O[di][mi][2] * inv[mi]) + 0x8000u;
      unsigned int u3 = __float_as_uint(O[di][mi][3] * inv[mi]) + 0x8000u;
      uint2 w;
      w.x = (u0 >> 16) | (u1 & 0xffff0000u);
      w.y = (u2 >> 16) | (u3 & 0xffff0000u);
      *(uint2*)&aog[rowbase + di * 16 + quad * 4] = w;
    }
  }
}

// ---------------- launch ----------------
extern "C" void kernel_launch(void* const* d_in, const int* in_sizes, int n_in,
                              void* d_out, int out_size, void* d_ws, size_t ws_size,
                              hipStream_t stream) {
  (void)in_sizes; (void)n_in; (void)out_size; (void)ws_size;
  const float* x  = (const float*)d_in[0];
  const float* te = (const float*)d_in[1];
  const float* Wq = (const float*)d_in[2];
  const float* Wk = (const float*)d_in[3];
  const float* Wv = (const float*)d_in[4];
  const float* Wo = (const float*)d_in[5];
  const float* bo = (const float*)d_in[6];
  const float* Wt = (const float*)d_in[7];
  const float* bt = (const float*)d_in[8];
  float* out = (float*)d_out;

  char* ws = (char*)d_ws;
  size_t off = 0;
  auto carve = [&](size_t bytes) -> void* {
    void* p = ws + off;
    off += (bytes + 255) & ~(size_t)255;
    return p;
  };
  float* twb            = (float*)carve(64 * sizeof(float));
  unsigned short* xb    = (unsigned short*)carve((size_t)MROWS * EMB * 2);   // 16 MB
  unsigned short* wqkvt = (unsigned short*)carve((size_t)3 * EMB * EMB * 2); //  6 MB
  unsigned short* wot   = (unsigned short*)carve((size_t)EMB * EMB * 2);     //  2 MB
  unsigned short* vtb   = (unsigned short*)carve((size_t)MROWS * EMB * 2);   // 16 MB
  // q/k live in d_out (8192*1024 fp32 = 32 MB = 2 * 16 MB bf16); both are dead before
  // gemm<1> overwrites d_out with the final result.
  unsigned short* qb    = (unsigned short*)d_out;
  unsigned short* kb    = (unsigned short*)d_out + (size_t)MROWS * EMB;
  unsigned short* ao    = xb;  // alias: xb is dead after GEMM0

  prelude_kernel<<<dim3(32, 32, 12), dim3(256), 0, stream>>>(
      x, xb, Wq, Wk, Wv, Wo, wqkvt, wot, te, Wt, bt, twb);
  gemm_kernel<0><<<dim3(12, 64), dim3(256), 0, stream>>>(xb, wqkvt, qb, kb, vtb, nullptr, nullptr, twb);
  attn_kernel<<<dim3(16, NH, NB), dim3(256), 0, stream>>>(qb, kb, vtb, ao);
  gemm_kernel<1><<<dim3(4, 64), dim3(256), 0, stream>>>(ao, wot, nullptr, nullptr, nullptr, out, bo, nullptr);
}